// Round 6
// baseline (4594.716 us; speedup 1.0000x reference)
//
#include <hip/hip_runtime.h>
#include <math.h>

// Problem constants
#define H_     8
#define D_     64
#define TOPK_  32
#define NUMB_  1000
#define DIM_   1024
#define BATCH_ 4
#define SEQ_   2048
#define INNER_ 512                  // H*D
#define TOK_   (BATCH_*SEQ_)        // 8192
#define ROWS_  (BATCH_*H_*SEQ_)     // 65536

// Phase split: 2 phases, each covers 2 batches = 4096 tokens = 32768 sim rows.
#define PH_TOK_  4096
#define PH_ROWS_ 32768

// ---------------------------------------------------------------------------
// Workspace layout — ~49 MiB.
//   [0)       dgo    float2[1000*64] (diag,o)   = 512,000 B
//   [512000)  kT     fp32 [64][1000]            = 256,000 B
//   [768000)  psiRow int[1000]                  =   4,000 B
//   [1 MiB)   V      fp32 8192*512              = 16 MiB
//   [17 MiB)  OutMid fp32 8192*512              = 16 MiB
//   [33 MiB)  Qh     fp64 4096*512              = 16 MiB (per-phase half)
// ---------------------------------------------------------------------------

// ---------------------------------------------------------------------------
// K0: dgo[n][d] = (b_mat[n][d][d], o_vec[n][d]); kT[d][n] = k_vec[n][d];
//     psiRow = -1.
// ---------------------------------------------------------------------------
__global__ void k0_prep(const float* __restrict__ b_mat,
                        const float* __restrict__ k_vec,
                        const float* __restrict__ o_vec,
                        float2* __restrict__ dgo,
                        float*  __restrict__ kT,
                        int*    __restrict__ psiRow) {
    int t = blockIdx.x * 256 + threadIdx.x;
    if (t < NUMB_ * D_) {
        int n = t >> 6, d = t & 63;
        dgo[t] = make_float2(b_mat[n * (D_ * D_) + d * (D_ + 1)], o_vec[t]);
        kT[d * NUMB_ + n] = k_vec[t];
    }
    if (t < NUMB_) psiRow[t] = -1;
}

// ---------------------------------------------------------------------------
// K1: qv = x @ W_qv, fp64 accumulation of exact fp32 products (unchanged).
// ---------------------------------------------------------------------------
#define BK1 16
__global__ __launch_bounds__(256) void k1_qv(const float* __restrict__ x,
                                             const float* __restrict__ Wqv,
                                             double* __restrict__ Qh,
                                             float*  __restrict__ V,
                                             int tokBase) {
    __shared__ float xs[64][BK1 + 1];
    __shared__ float ws[BK1][64 + 1];
    const int tx = threadIdx.x & 15, ty = threadIdx.x >> 4;
    const int mBase = tokBase + blockIdx.y * 64;
    const int nBase = blockIdx.x * 64;

    double acc[4][4];
#pragma unroll
    for (int a = 0; a < 4; a++)
#pragma unroll
        for (int b = 0; b < 4; b++) acc[a][b] = 0.0;

    for (int k0 = 0; k0 < DIM_; k0 += BK1) {
        for (int i = threadIdx.x; i < 64 * BK1; i += 256) {
            int r = i >> 4, kk = i & 15;
            xs[r][kk] = x[(size_t)(mBase + r) * DIM_ + k0 + kk];
        }
        for (int i = threadIdx.x; i < BK1 * 64; i += 256) {
            int kk = i >> 6, c = i & 63;
            ws[kk][c] = Wqv[(size_t)(k0 + kk) * (2 * INNER_) + nBase + c];
        }
        __syncthreads();
#pragma unroll
        for (int kk = 0; kk < BK1; ++kk) {
            float xa[4], wb[4];
#pragma unroll
            for (int a = 0; a < 4; a++) xa[a] = xs[ty * 4 + a][kk];
#pragma unroll
            for (int b = 0; b < 4; b++) wb[b] = ws[kk][tx * 4 + b];
#pragma unroll
            for (int a = 0; a < 4; a++)
#pragma unroll
                for (int b = 0; b < 4; b++)
                    acc[a][b] += (double)xa[a] * (double)wb[b];
        }
        __syncthreads();
    }

    const int mr = mBase + ty * 4, nc = nBase + tx * 4;
    if (nc < INNER_) {
#pragma unroll
        for (int a = 0; a < 4; a++)
#pragma unroll
            for (int b = 0; b < 4; b++)
                Qh[(size_t)(mr - tokBase + a) * INNER_ + nc + b] = acc[a][b];
    } else {
#pragma unroll
        for (int a = 0; a < 4; a++)
#pragma unroll
            for (int b = 0; b < 4; b++)
                V[(size_t)(mr + a) * INNER_ + (nc - INNER_) + b] = (float)acc[a][b];
    }
}

// ---------------------------------------------------------------------------
// K2 v3: one wave = 4 rows. fp64 sim dot in 4 slot-groups (acc[4][4] live =
//   32 VGPR, no spill), demoted per-group to monotone fp32 keys. Top-32 via
//   ballot bit-descent on keys. Fast path (ceq==needed): members = key>=tau,
//   compacted to LDS by ballot-rank, lane-parallel exp + butterfly esum,
//   unrolled 32-member gather from fused (diag,o) table. Rare boundary
//   collisions: fp64 recompute (same d-order/fma => bitwise == original acc)
//   + butterfly argmax, round-5 semantics. Selection set bit-identical to
//   exact-fp64 top-k with (value desc, index asc) ties.
// ---------------------------------------------------------------------------
__device__ __forceinline__ unsigned ordkey(float f) {
    unsigned u = __float_as_uint(f);
    return (u & 0x80000000u) ? ~u : (u | 0x80000000u);
}
__device__ __forceinline__ float ordinv(unsigned k) {
    return __uint_as_float((k & 0x80000000u) ? (k & 0x7fffffffu) : ~k);
}

__global__ __launch_bounds__(256, 1) void k2_sim(const double* __restrict__ Qh,
                                                 const float*  __restrict__ V,
                                                 const float*  __restrict__ kT,
                                                 const float2* __restrict__ dgo,
                                                 float* __restrict__ OutMid,
                                                 int*   __restrict__ psiRow,
                                                 int sBase0, int tokOff) {
    __shared__ double qld[4][4][64];          // [wave][row][d]
    __shared__ uint2  mlist[4][TOPK_];        // [wave][member] = (n, simf bits)
    const int lane = threadIdx.x & 63;
    const int wid  = threadIdx.x >> 6;
    const int sBase = sBase0 + (blockIdx.x * 4 + wid) * 4;

#pragma unroll
    for (int r = 0; r < 4; r++) {
        int s = sBase + r;
        int b = s >> 14, h = (s >> 11) & 7, i = s & 2047;
        int tok = b * SEQ_ + i;
        qld[wid][r][lane] = Qh[(size_t)(tok - tokOff) * INNER_ + h * D_ + lane];
    }
    __syncthreads();

    unsigned key[4][16];

    // ---- dot in slot-groups of 4 (32 VGPR acc), demote to fp32 keys ----
#define DO_SG(SG)                                                             \
    {                                                                         \
        double acc[4][4];                                                     \
        _Pragma("unroll")                                                     \
        for (int r = 0; r < 4; r++)                                           \
            _Pragma("unroll")                                                 \
            for (int j = 0; j < 4; j++) acc[r][j] = 0.0;                      \
        for (int d = 0; d < 64; ++d) {                                        \
            double q0 = qld[wid][0][d], q1 = qld[wid][1][d];                  \
            double q2 = qld[wid][2][d], q3 = qld[wid][3][d];                  \
            const float* kp = kT + d * NUMB_;                                 \
            _Pragma("unroll")                                                 \
            for (int j = 0; j < 4; j++) {                                     \
                int n = ((SG) * 4 + j) * 64 + lane;                           \
                float kv = (n < NUMB_) ? kp[n] : 0.f;                         \
                double kd = (double)kv;                                       \
                acc[0][j] += q0 * kd;                                         \
                acc[1][j] += q1 * kd;                                         \
                acc[2][j] += q2 * kd;                                         \
                acc[3][j] += q3 * kd;                                         \
            }                                                                 \
        }                                                                     \
        _Pragma("unroll")                                                     \
        for (int r = 0; r < 4; r++)                                           \
            _Pragma("unroll")                                                 \
            for (int j = 0; j < 4; j++) {                                     \
                int n = ((SG) * 4 + j) * 64 + lane;                           \
                key[r][(SG) * 4 + j] =                                        \
                    (n < NUMB_) ? ordkey((float)acc[r][j]) : 0u;              \
            }                                                                 \
    }                                                                         \
    __builtin_amdgcn_sched_barrier(0);

    DO_SG(0)
    DO_SG(1)
    DO_SG(2)
    DO_SG(3)
#undef DO_SG

    // ---- per-row top-k + epilogue ----
#pragma unroll 1
    for (int r = 0; r < 4; ++r) {
        const int s = sBase + r;
        const int b = s >> 14, h = (s >> 11) & 7, ii = s & 2047;
        const int tok = b * SEQ_ + ii;
        const float vlane = V[(size_t)tok * INNER_ + h * D_ + lane];

        // bit-descent: tau = 32nd-largest key
        unsigned tau = 0u;
        for (int bit = 31; bit >= 0; --bit) {
            unsigned cand = tau | (1u << bit);
            int c = 0;
#pragma unroll
            for (int nb = 0; nb < 16; ++nb)
                c += __popcll(__ballot(key[r][nb] >= cand));
            if (c >= TOPK_) tau = cand;
        }

        int cgt = 0, ceq = 0;
#pragma unroll
        for (int nb = 0; nb < 16; ++nb) {
            cgt += __popcll(__ballot(key[r][nb] > tau));
            ceq += __popcll(__ballot(key[r][nb] == tau));
        }
        const int needed = TOPK_ - cgt;   // >= 1 by construction

        float esum, outAcc = 0.f;

        if (ceq == needed) {
            // ---------- fast path: members are exactly key >= tau ----------
            int base = 0;
#pragma unroll
            for (int nb = 0; nb < 16; ++nb) {
                unsigned kk = key[r][nb];
                bool sel = (kk >= tau);
                unsigned long long mm = __ballot(sel);
                if (sel) {
                    int n = nb * 64 + lane;
                    int pos = base + __popcll(mm & ((1ull << lane) - 1ull));
                    mlist[wid][pos] =
                        make_uint2((unsigned)n, __float_as_uint(ordinv(kk)));
                    atomicMax(psiRow + n, s);
                }
                base += __popcll(mm);
            }
            // lane-parallel exp (lanes 32-63 mirror 0-31)
            uint2 rec = mlist[wid][lane & 31];
            float myek = expf(__uint_as_float(rec.y) * 0.125f);
            float e = myek;
#pragma unroll
            for (int off = 1; off <= 16; off <<= 1)
                e += __shfl_xor(e, off);
            esum = e;
            // unrolled member gather: loads pipeline
#pragma unroll
            for (int k = 0; k < TOPK_; ++k) {
                int   nk = __shfl((int)rec.x, k);
                float ek = __shfl(myek, k);
                float2 g = dgo[nk * 64 + lane];
                float mpot = g.x * vlane;
                if (mpot > 0.f) outAcc += ek * g.y;
            }
        } else {
            // ---------- rare path: fp32-key collision at the boundary ------
            esum = 0.f;
#pragma unroll
            for (int nb = 0; nb < 16; ++nb) {
                unsigned kk = key[r][nb];
                bool isgt = (kk > tau);
                unsigned long long mm = __ballot(isgt);
                if (isgt) atomicMax(psiRow + nb * 64 + lane, s);
                while (mm) {
                    int l = __ffsll((unsigned long long)mm) - 1; mm &= mm - 1;
                    int n = nb * 64 + l;
                    unsigned kr = (unsigned)__shfl((int)kk, l);
                    float ek = expf(ordinv(kr) * 0.125f);
                    esum += ek;
                    float2 g = dgo[n * 64 + lane];
                    float mpot = g.x * vlane;
                    if (mpot > 0.f) outAcc += ek * g.y;
                }
            }
            // fp64 recompute for eq slots (same d-order + fma => bitwise
            // identical to the original accumulation)
            double eqsim[16];
#pragma unroll
            for (int nb = 0; nb < 16; ++nb) {
                eqsim[nb] = -1e300;
                if (key[r][nb] == tau) {
                    double sacc = 0.0;
                    for (int d = 0; d < 64; ++d)
                        sacc += qld[wid][r][d] *
                                (double)kT[d * NUMB_ + nb * 64 + lane];
                    eqsim[nb] = sacc;
                }
            }
            unsigned takenMask = 0u;
            for (int t = 0; t < needed; ++t) {
                double bv = -1e300; int bn = 0x7fffffff;
#pragma unroll
                for (int nb = 0; nb < 16; ++nb) {
                    bool candt = (key[r][nb] == tau) && !(takenMask & (1u << nb));
                    double v = eqsim[nb];
                    int n = nb * 64 + lane;
                    if (candt && (v > bv || (v == bv && n < bn))) { bv = v; bn = n; }
                }
                for (int off = 32; off; off >>= 1) {
                    double ov = __shfl_xor(bv, off);
                    int    on = __shfl_xor(bn, off);
                    if (ov > bv || (ov == bv && on < bn)) { bv = ov; bn = on; }
                }
                if ((bn & 63) == lane) takenMask |= 1u << (bn >> 6);
                float ek = expf((float)bv * 0.125f);
                esum += ek;
                float2 g = dgo[bn * 64 + lane];
                float mpot = g.x * vlane;
                if (mpot > 0.f) outAcc += ek * g.y;
                if (lane == 0) atomicMax(psiRow + bn, s);
            }
        }

        OutMid[(size_t)tok * INNER_ + h * D_ + lane] = outAcc / esum;
    }
}

// ---------------------------------------------------------------------------
// K3: final = OutMid(8192x512) @ W_out(512x1024) + b_out -> fp32 d_out
// ---------------------------------------------------------------------------
#define BK3 16
__global__ __launch_bounds__(256) void k3_out(const float* __restrict__ A,
                                              const float* __restrict__ Wout,
                                              const float* __restrict__ bout,
                                              float* __restrict__ out) {
    __shared__ float as[64][BK3 + 1];
    __shared__ float bs[BK3][64 + 1];
    const int tx = threadIdx.x & 15, ty = threadIdx.x >> 4;
    const int mBase = blockIdx.y * 64, nBase = blockIdx.x * 64;

    float acc[4][4];
#pragma unroll
    for (int a = 0; a < 4; a++)
#pragma unroll
        for (int b = 0; b < 4; b++) acc[a][b] = 0.f;

    for (int k0 = 0; k0 < INNER_; k0 += BK3) {
        for (int i = threadIdx.x; i < 64 * BK3; i += 256) {
            int r = i >> 4, kk = i & 15;
            as[r][kk] = A[(size_t)(mBase + r) * INNER_ + k0 + kk];
        }
        for (int i = threadIdx.x; i < BK3 * 64; i += 256) {
            int kk = i >> 6, c = i & 63;
            bs[kk][c] = Wout[(size_t)(k0 + kk) * DIM_ + nBase + c];
        }
        __syncthreads();
#pragma unroll
        for (int kk = 0; kk < BK3; ++kk) {
            float xa[4], wb[4];
#pragma unroll
            for (int a = 0; a < 4; a++) xa[a] = as[ty * 4 + a][kk];
#pragma unroll
            for (int b = 0; b < 4; b++) wb[b] = bs[kk][tx * 4 + b];
#pragma unroll
            for (int a = 0; a < 4; a++)
#pragma unroll
                for (int b = 0; b < 4; b++)
                    acc[a][b] += xa[a] * wb[b];
        }
        __syncthreads();
    }

    const int mr = mBase + ty * 4, nc = nBase + tx * 4;
#pragma unroll
    for (int a = 0; a < 4; a++)
#pragma unroll
        for (int b = 0; b < 4; b++)
            out[(size_t)(mr + a) * DIM_ + nc + b] = acc[a][b] + bout[nc + b];
}

// ---------------------------------------------------------------------------
// K4: psi[n][d] = winner<0 ? 0 : (1-sigmoid(m))*m, m = diag[n][d]*v[s][d]
// ---------------------------------------------------------------------------
__global__ void k4_psi(const int*    __restrict__ psiRow,
                       const float*  __restrict__ V,
                       const float2* __restrict__ dgo,
                       float* __restrict__ psiOut) {
    int t = blockIdx.x * 256 + threadIdx.x;
    if (t >= NUMB_ * D_) return;
    int n = t >> 6, d = t & 63;
    int s = psiRow[n];
    float val = 0.f;
    if (s >= 0) {
        int b = s >> 14, h = (s >> 11) & 7, i = s & 2047;
        int tok = b * SEQ_ + i;
        float v  = V[(size_t)tok * INNER_ + h * D_ + d];
        float m  = dgo[t].x * v;
        float sg = 1.f / (1.f + expf(-m));
        val = (1.f - sg) * m;
    }
    psiOut[t] = val;
}

// ---------------------------------------------------------------------------
extern "C" void kernel_launch(void* const* d_in, const int* in_sizes, int n_in,
                              void* d_out, int out_size, void* d_ws, size_t ws_size,
                              hipStream_t stream) {
    const float* x    = (const float*)d_in[0];
    const float* Wqv  = (const float*)d_in[1];
    const float* Wout = (const float*)d_in[2];
    const float* bout = (const float*)d_in[3];
    const float* bmat = (const float*)d_in[4];
    const float* kvec = (const float*)d_in[5];
    const float* ovec = (const float*)d_in[6];
    float* out = (float*)d_out;   // reference outputs are float32

    char* ws = (char*)d_ws;
    float2* dgo    = (float2*)(ws);                       //   512,000 B
    float*  kT     = (float*) (ws + 512000);              //   256,000 B
    int*    psiRow = (int*)   (ws + 768000);              //     4,000 B
    float*  V      = (float*) (ws + (1u  << 20));         // 16 MiB
    float*  OutMid = (float*) (ws + (17u << 20));         // 16 MiB
    double* Qh     = (double*)(ws + (33u << 20));         // 16 MiB

    k0_prep<<<(NUMB_ * D_ + 255) / 256, 256, 0, stream>>>(bmat, kvec, ovec,
                                                          dgo, kT, psiRow);

    for (int p = 0; p < 2; ++p) {
        k1_qv <<<dim3(16, PH_TOK_ / 64), 256, 0, stream>>>(x, Wqv, Qh, V, p * PH_TOK_);
        k2_sim<<<PH_ROWS_ / 16, 256, 0, stream>>>(Qh, V, kT, dgo, OutMid,
                                                  psiRow, p * PH_ROWS_, p * PH_TOK_);
    }

    k3_out<<<dim3(16, 128), 256, 0, stream>>>(OutMid, Wout, bout, out);
    k4_psi<<<(NUMB_ * D_ + 255) / 256, 256, 0, stream>>>(psiRow, V, dgo,
                                                         out + (size_t)TOK_ * DIM_);
}

// Round 7
// 4152.047 us; speedup vs baseline: 1.1066x; 1.1066x over previous
//
#include <hip/hip_runtime.h>
#include <math.h>

// Problem constants
#define H_     8
#define D_     64
#define TOPK_  32
#define NUMB_  1000
#define DIM_   1024
#define BATCH_ 4
#define SEQ_   2048
#define INNER_ 512                  // H*D
#define TOK_   (BATCH_*SEQ_)        // 8192
#define ROWS_  (BATCH_*H_*SEQ_)     // 65536

// Phase split: 2 phases, each covers 2 batches = 4096 tokens = 32768 sim rows.
#define PH_TOK_  4096
#define PH_ROWS_ 32768

// ---------------------------------------------------------------------------
// Workspace layout — ~49 MiB.
//   [0)       dgo    float2[1000*64] (diag,o)   = 512,000 B
//   [512000)  kT     fp32 [64][1000]            = 256,000 B
//   [768000)  psiRow int[1000]                  =   4,000 B
//   [1 MiB)   V      fp32 8192*512              = 16 MiB
//   [17 MiB)  OutMid fp32 8192*512              = 16 MiB
//   [33 MiB)  Qh     fp64 4096*512              = 16 MiB (per-phase half)
// ---------------------------------------------------------------------------

__global__ void k0_prep(const float* __restrict__ b_mat,
                        const float* __restrict__ k_vec,
                        const float* __restrict__ o_vec,
                        float2* __restrict__ dgo,
                        float*  __restrict__ kT,
                        int*    __restrict__ psiRow) {
    int t = blockIdx.x * 256 + threadIdx.x;
    if (t < NUMB_ * D_) {
        int n = t >> 6, d = t & 63;
        dgo[t] = make_float2(b_mat[n * (D_ * D_) + d * (D_ + 1)], o_vec[t]);
        kT[d * NUMB_ + n] = k_vec[t];
    }
    if (t < NUMB_) psiRow[t] = -1;
}

// ---------------------------------------------------------------------------
// K1: qv = x @ W_qv, fp64 accumulation of exact fp32 products (unchanged).
// ---------------------------------------------------------------------------
#define BK1 16
__global__ __launch_bounds__(256) void k1_qv(const float* __restrict__ x,
                                             const float* __restrict__ Wqv,
                                             double* __restrict__ Qh,
                                             float*  __restrict__ V,
                                             int tokBase) {
    __shared__ float xs[64][BK1 + 1];
    __shared__ float ws[BK1][64 + 1];
    const int tx = threadIdx.x & 15, ty = threadIdx.x >> 4;
    const int mBase = tokBase + blockIdx.y * 64;
    const int nBase = blockIdx.x * 64;

    double acc[4][4];
#pragma unroll
    for (int a = 0; a < 4; a++)
#pragma unroll
        for (int b = 0; b < 4; b++) acc[a][b] = 0.0;

    for (int k0 = 0; k0 < DIM_; k0 += BK1) {
        for (int i = threadIdx.x; i < 64 * BK1; i += 256) {
            int r = i >> 4, kk = i & 15;
            xs[r][kk] = x[(size_t)(mBase + r) * DIM_ + k0 + kk];
        }
        for (int i = threadIdx.x; i < BK1 * 64; i += 256) {
            int kk = i >> 6, c = i & 63;
            ws[kk][c] = Wqv[(size_t)(k0 + kk) * (2 * INNER_) + nBase + c];
        }
        __syncthreads();
#pragma unroll
        for (int kk = 0; kk < BK1; ++kk) {
            float xa[4], wb[4];
#pragma unroll
            for (int a = 0; a < 4; a++) xa[a] = xs[ty * 4 + a][kk];
#pragma unroll
            for (int b = 0; b < 4; b++) wb[b] = ws[kk][tx * 4 + b];
#pragma unroll
            for (int a = 0; a < 4; a++)
#pragma unroll
                for (int b = 0; b < 4; b++)
                    acc[a][b] += (double)xa[a] * (double)wb[b];
        }
        __syncthreads();
    }

    const int mr = mBase + ty * 4, nc = nBase + tx * 4;
    if (nc < INNER_) {
#pragma unroll
        for (int a = 0; a < 4; a++)
#pragma unroll
            for (int b = 0; b < 4; b++)
                Qh[(size_t)(mr - tokBase + a) * INNER_ + nc + b] = acc[a][b];
    } else {
#pragma unroll
        for (int a = 0; a < 4; a++)
#pragma unroll
            for (int b = 0; b < 4; b++)
                V[(size_t)(mr + a) * INNER_ + (nc - INNER_) + b] = (float)acc[a][b];
    }
}

// ---------------------------------------------------------------------------
// K2 v4: one wave = 4 rows. fp64 dot split over n-dimension into two halves
//   (acc[4][8] = 64 VGPR live; keys demoted per half; sched_barrier between)
//   — NO runtime-indexed private arrays anywhere (round-6 lesson), NO AGPR
//   overflow (round-5 lesson). Top-32 via ballot bit-descent on monotone fp32
//   keys; fast path compacts members to LDS, lane-parallel exp + butterfly
//   esum, unrolled 32-member gather. Rare fp32-key boundary collisions:
//   fp64 recompute (same fma/d-order => bitwise == discarded acc) via LDS
//   scratch + butterfly argmax. Selection set bit-identical to exact-fp64
//   top-k with (value desc, index asc) ties.
// ---------------------------------------------------------------------------
__device__ __forceinline__ unsigned ordkey(float f) {
    unsigned u = __float_as_uint(f);
    return (u & 0x80000000u) ? ~u : (u | 0x80000000u);
}
__device__ __forceinline__ float ordinv(unsigned k) {
    return __uint_as_float((k & 0x80000000u) ? (k & 0x7fffffffu) : ~k);
}

__global__ __launch_bounds__(256, 2) void k2_sim(const double* __restrict__ Qh,
                                                 const float*  __restrict__ V,
                                                 const float*  __restrict__ kT,
                                                 const float2* __restrict__ dgo,
                                                 float* __restrict__ OutMid,
                                                 int*   __restrict__ psiRow,
                                                 int sBase0, int tokOff) {
    __shared__ double qld[4][4][64];          // [wave][row][d]
    __shared__ uint2  mlist[4][TOPK_];        // [wave][member] = (n, simf bits)
    __shared__ double eqs[4][16];             // [wave][nb] rare-path fp64 sims
    const int lane = threadIdx.x & 63;
    const int wid  = threadIdx.x >> 6;
    const int sBase = sBase0 + (blockIdx.x * 4 + wid) * 4;

#pragma unroll
    for (int r = 0; r < 4; r++) {
        int s = sBase + r;
        int b = s >> 14, h = (s >> 11) & 7, i = s & 2047;
        int tok = b * SEQ_ + i;
        qld[wid][r][lane] = Qh[(size_t)(tok - tokOff) * INNER_ + h * D_ + lane];
    }
    __syncthreads();

    unsigned key[4][16];   // written with compile-time indices only

    // ---- dot over n-halves: acc[4][8] (64 VGPR) live per half ----
#define DO_HALF(HH)                                                           \
    {                                                                         \
        double acc[4][8];                                                     \
        _Pragma("unroll")                                                     \
        for (int r = 0; r < 4; r++)                                           \
            _Pragma("unroll")                                                 \
            for (int j = 0; j < 8; j++) acc[r][j] = 0.0;                      \
        for (int d = 0; d < 64; ++d) {                                        \
            double q0 = qld[wid][0][d], q1 = qld[wid][1][d];                  \
            double q2 = qld[wid][2][d], q3 = qld[wid][3][d];                  \
            const float* kp = kT + d * NUMB_;                                 \
            _Pragma("unroll")                                                 \
            for (int j = 0; j < 8; j++) {                                     \
                int n = ((HH) * 8 + j) * 64 + lane;                           \
                float kv = (n < NUMB_) ? kp[n] : 0.f;                         \
                double kd = (double)kv;                                       \
                acc[0][j] = fma(q0, kd, acc[0][j]);                           \
                acc[1][j] = fma(q1, kd, acc[1][j]);                           \
                acc[2][j] = fma(q2, kd, acc[2][j]);                           \
                acc[3][j] = fma(q3, kd, acc[3][j]);                           \
            }                                                                 \
        }                                                                     \
        _Pragma("unroll")                                                     \
        for (int r = 0; r < 4; r++)                                           \
            _Pragma("unroll")                                                 \
            for (int j = 0; j < 8; j++) {                                     \
                int n = ((HH) * 8 + j) * 64 + lane;                           \
                key[r][(HH) * 8 + j] =                                        \
                    (n < NUMB_) ? ordkey((float)acc[r][j]) : 0u;              \
            }                                                                 \
    }                                                                         \
    __builtin_amdgcn_sched_barrier(0);

    DO_HALF(0)
    DO_HALF(1)
#undef DO_HALF

    // ---- per-row top-k + epilogue (r fully unrolled: static key indexing) --
#pragma unroll
    for (int r = 0; r < 4; ++r) {
        const int s = sBase + r;
        const int b = s >> 14, h = (s >> 11) & 7, ii = s & 2047;
        const int tok = b * SEQ_ + ii;
        const float vlane = V[(size_t)tok * INNER_ + h * D_ + lane];

        // bit-descent: tau = 32nd-largest key
        unsigned tau = 0u;
        for (int bit = 31; bit >= 0; --bit) {
            unsigned cand = tau | (1u << bit);
            int c = 0;
#pragma unroll
            for (int nb = 0; nb < 16; ++nb)
                c += __popcll(__ballot(key[r][nb] >= cand));
            if (c >= TOPK_) tau = cand;
        }

        int cgt = 0, ceq = 0;
#pragma unroll
        for (int nb = 0; nb < 16; ++nb) {
            cgt += __popcll(__ballot(key[r][nb] > tau));
            ceq += __popcll(__ballot(key[r][nb] == tau));
        }
        const int needed = TOPK_ - cgt;   // >= 1 by construction

        float esum, outAcc = 0.f;

        if (ceq == needed) {
            // ---------- fast path: members are exactly key >= tau ----------
            int base = 0;
#pragma unroll
            for (int nb = 0; nb < 16; ++nb) {
                unsigned kk = key[r][nb];
                bool sel = (kk >= tau);
                unsigned long long mm = __ballot(sel);
                if (sel) {
                    int n = nb * 64 + lane;
                    int pos = base + __popcll(mm & ((1ull << lane) - 1ull));
                    mlist[wid][pos] =
                        make_uint2((unsigned)n, __float_as_uint(ordinv(kk)));
                    atomicMax(psiRow + n, s);
                }
                base += __popcll(mm);
            }
            // lane-parallel exp (lanes 32-63 mirror 0-31)
            uint2 rec = mlist[wid][lane & 31];
            float myek = expf(__uint_as_float(rec.y) * 0.125f);
            float e = myek;
#pragma unroll
            for (int off = 1; off <= 16; off <<= 1)
                e += __shfl_xor(e, off);
            esum = e;
            // unrolled member gather: loads pipeline
#pragma unroll
            for (int k = 0; k < TOPK_; ++k) {
                int   nk = __shfl((int)rec.x, k);
                float ek = __shfl(myek, k);
                float2 g = dgo[nk * 64 + lane];
                float mpot = g.x * vlane;
                if (mpot > 0.f) outAcc += ek * g.y;
            }
        } else {
            // ---------- rare path: fp32-key collision at the boundary ------
            esum = 0.f;
#pragma unroll
            for (int nb = 0; nb < 16; ++nb) {
                unsigned kk = key[r][nb];
                bool isgt = (kk > tau);
                unsigned long long mm = __ballot(isgt);
                if (isgt) atomicMax(psiRow + nb * 64 + lane, s);
                while (mm) {
                    int l = __ffsll((unsigned long long)mm) - 1; mm &= mm - 1;
                    int n = nb * 64 + l;
                    unsigned kr = (unsigned)__shfl((int)kk, l);
                    float ek = expf(ordinv(kr) * 0.125f);
                    esum += ek;
                    float2 g = dgo[n * 64 + lane];
                    float mpot = g.x * vlane;
                    if (mpot > 0.f) outAcc += ek * g.y;
                }
            }
            // fp64 recompute for eq slots into LDS (same fma/d-order =>
            // bitwise identical to the discarded accumulation)
#pragma unroll
            for (int nb = 0; nb < 16; ++nb) {
                if (key[r][nb] == tau) {
                    double sacc = 0.0;
                    int n = nb * 64 + lane;
                    for (int d = 0; d < 64; ++d) {
                        float kv = (n < NUMB_) ? kT[d * NUMB_ + n] : 0.f;
                        sacc = fma(qld[wid][r][d], (double)kv, sacc);
                    }
                    eqs[wid][nb] = sacc;   // only consumed under same cond
                }
            }
            unsigned takenMask = 0u;
            for (int t = 0; t < needed; ++t) {
                double bv = -1e300; int bn = 0x7fffffff;
#pragma unroll
                for (int nb = 0; nb < 16; ++nb) {
                    bool candt = (key[r][nb] == tau) && !(takenMask & (1u << nb));
                    if (candt) {
                        double v = eqs[wid][nb];
                        int n = nb * 64 + lane;
                        if (v > bv || (v == bv && n < bn)) { bv = v; bn = n; }
                    }
                }
                for (int off = 32; off; off >>= 1) {
                    double ov = __shfl_xor(bv, off);
                    int    on = __shfl_xor(bn, off);
                    if (ov > bv || (ov == bv && on < bn)) { bv = ov; bn = on; }
                }
                if ((bn & 63) == lane) takenMask |= 1u << (bn >> 6);
                float ek = expf((float)bv * 0.125f);
                esum += ek;
                float2 g = dgo[bn * 64 + lane];
                float mpot = g.x * vlane;
                if (mpot > 0.f) outAcc += ek * g.y;
                if (lane == 0) atomicMax(psiRow + bn, s);
            }
        }

        OutMid[(size_t)tok * INNER_ + h * D_ + lane] = outAcc / esum;
    }
}

// ---------------------------------------------------------------------------
// K3: final = OutMid(8192x512) @ W_out(512x1024) + b_out -> fp32 d_out
// ---------------------------------------------------------------------------
#define BK3 16
__global__ __launch_bounds__(256) void k3_out(const float* __restrict__ A,
                                              const float* __restrict__ Wout,
                                              const float* __restrict__ bout,
                                              float* __restrict__ out) {
    __shared__ float as[64][BK3 + 1];
    __shared__ float bs[BK3][64 + 1];
    const int tx = threadIdx.x & 15, ty = threadIdx.x >> 4;
    const int mBase = blockIdx.y * 64, nBase = blockIdx.x * 64;

    float acc[4][4];
#pragma unroll
    for (int a = 0; a < 4; a++)
#pragma unroll
        for (int b = 0; b < 4; b++) acc[a][b] = 0.f;

    for (int k0 = 0; k0 < INNER_; k0 += BK3) {
        for (int i = threadIdx.x; i < 64 * BK3; i += 256) {
            int r = i >> 4, kk = i & 15;
            as[r][kk] = A[(size_t)(mBase + r) * INNER_ + k0 + kk];
        }
        for (int i = threadIdx.x; i < BK3 * 64; i += 256) {
            int kk = i >> 6, c = i & 63;
            bs[kk][c] = Wout[(size_t)(k0 + kk) * DIM_ + nBase + c];
        }
        __syncthreads();
#pragma unroll
        for (int kk = 0; kk < BK3; ++kk) {
            float xa[4], wb[4];
#pragma unroll
            for (int a = 0; a < 4; a++) xa[a] = as[ty * 4 + a][kk];
#pragma unroll
            for (int b = 0; b < 4; b++) wb[b] = bs[kk][tx * 4 + b];
#pragma unroll
            for (int a = 0; a < 4; a++)
#pragma unroll
                for (int b = 0; b < 4; b++)
                    acc[a][b] += xa[a] * wb[b];
        }
        __syncthreads();
    }

    const int mr = mBase + ty * 4, nc = nBase + tx * 4;
#pragma unroll
    for (int a = 0; a < 4; a++)
#pragma unroll
        for (int b = 0; b < 4; b++)
            out[(size_t)(mr + a) * DIM_ + nc + b] = acc[a][b] + bout[nc + b];
}

// ---------------------------------------------------------------------------
// K4: psi[n][d] = winner<0 ? 0 : (1-sigmoid(m))*m, m = diag[n][d]*v[s][d]
// ---------------------------------------------------------------------------
__global__ void k4_psi(const int*    __restrict__ psiRow,
                       const float*  __restrict__ V,
                       const float2* __restrict__ dgo,
                       float* __restrict__ psiOut) {
    int t = blockIdx.x * 256 + threadIdx.x;
    if (t >= NUMB_ * D_) return;
    int n = t >> 6, d = t & 63;
    int s = psiRow[n];
    float val = 0.f;
    if (s >= 0) {
        int b = s >> 14, h = (s >> 11) & 7, i = s & 2047;
        int tok = b * SEQ_ + i;
        float v  = V[(size_t)tok * INNER_ + h * D_ + d];
        float m  = dgo[t].x * v;
        float sg = 1.f / (1.f + expf(-m));
        val = (1.f - sg) * m;
    }
    psiOut[t] = val;
}

// ---------------------------------------------------------------------------
extern "C" void kernel_launch(void* const* d_in, const int* in_sizes, int n_in,
                              void* d_out, int out_size, void* d_ws, size_t ws_size,
                              hipStream_t stream) {
    const float* x    = (const float*)d_in[0];
    const float* Wqv  = (const float*)d_in[1];
    const float* Wout = (const float*)d_in[2];
    const float* bout = (const float*)d_in[3];
    const float* bmat = (const float*)d_in[4];
    const float* kvec = (const float*)d_in[5];
    const float* ovec = (const float*)d_in[6];
    float* out = (float*)d_out;   // reference outputs are float32

    char* ws = (char*)d_ws;
    float2* dgo    = (float2*)(ws);                       //   512,000 B
    float*  kT     = (float*) (ws + 512000);              //   256,000 B
    int*    psiRow = (int*)   (ws + 768000);              //     4,000 B
    float*  V      = (float*) (ws + (1u  << 20));         // 16 MiB
    float*  OutMid = (float*) (ws + (17u << 20));         // 16 MiB
    double* Qh     = (double*)(ws + (33u << 20));         // 16 MiB

    k0_prep<<<(NUMB_ * D_ + 255) / 256, 256, 0, stream>>>(bmat, kvec, ovec,
                                                          dgo, kT, psiRow);

    for (int p = 0; p < 2; ++p) {
        k1_qv <<<dim3(16, PH_TOK_ / 64), 256, 0, stream>>>(x, Wqv, Qh, V, p * PH_TOK_);
        k2_sim<<<PH_ROWS_ / 16, 256, 0, stream>>>(Qh, V, kT, dgo, OutMid,
                                                  psiRow, p * PH_ROWS_, p * PH_TOK_);
    }

    k3_out<<<dim3(16, 128), 256, 0, stream>>>(OutMid, Wout, bout, out);
    k4_psi<<<(NUMB_ * D_ + 255) / 256, 256, 0, stream>>>(psiRow, V, dgo,
                                                         out + (size_t)TOK_ * DIM_);
}